// Round 1
// baseline (2584.879 us; speedup 1.0000x reference)
//
#include <hip/hip_runtime.h>
#include <hip/hip_bf16.h>

#define NUM_USER 300000
#define NUM_ITEM 200000
#define NTOT (NUM_USER + NUM_ITEM)
#define D 64

// Phase 1: edge scatter. One 64-lane wave per edge; lane i handles dim i.
// agg (= d_out) must be zeroed beforehand.
__global__ __launch_bounds__(256) void scatter_kernel(
    const float* __restrict__ users_emb,
    const float* __restrict__ items_emb,
    const float* __restrict__ vals,
    const int*   __restrict__ rows,
    const int*   __restrict__ cols,
    float* __restrict__ agg,
    int nnz)
{
    int e = blockIdx.x * 4 + (threadIdx.x >> 6);
    int lane = threadIdx.x & 63;
    if (e >= nnz) return;
    int r = rows[e];
    int c = cols[e];
    float v = vals[e];
    // wave-uniform branch (c is the same for all 64 lanes of this edge)
    const float* src = (c < NUM_USER) ? (users_emb + (size_t)c * D)
                                      : (items_emb + (size_t)(c - NUM_USER) * D);
    float m = v * src[lane];
    atomicAdd(&agg[(size_t)r * D + lane], m);
}

// Phase 2: in-place per-row transform out_row = leaky_relu(agg_row @ w).
// Each block owns 16 rows exclusively: stage to LDS, compute, overwrite.
__global__ __launch_bounds__(256) void rowgemm_kernel(
    float* __restrict__ out,
    const float* __restrict__ w,
    int n)
{
    __shared__ float ws[D * D];   // 16 KB
    __shared__ float as[16 * D];  // 4 KB
    int tid = threadIdx.x;

    // stage w (64x64 fp32) via float4: 1024 float4s / 256 threads = 4 each
    const float4* w4 = (const float4*)w;
    float4* ws4 = (float4*)ws;
    #pragma unroll
    for (int i = 0; i < 4; i++) ws4[tid + i * 256] = w4[tid + i * 256];

    // stage 16 rows of agg (16*64 floats = 256 float4s), coalesced
    size_t row0 = (size_t)blockIdx.x * 16;
    ((float4*)as)[tid] = ((const float4*)(out + row0 * D))[tid];
    __syncthreads();

    int col  = tid & 63;   // 0..63
    int rsub = tid >> 6;   // 0..3 (wave id — wave-uniform)
    float res[4];
    #pragma unroll
    for (int rr = 0; rr < 4; rr++) {
        int row = rr * 4 + rsub;
        float acc = 0.f;
        #pragma unroll
        for (int k = 0; k < D; k++) {
            // as[row*64+k]: wave-uniform address -> broadcast, conflict-free
            // ws[k*64+col]: lanes map to bank col%32 -> 2-way, free on CDNA4
            acc = fmaf(as[row * D + k], ws[k * D + col], acc);
        }
        res[rr] = acc > 0.f ? acc : 0.2f * acc;
    }

    #pragma unroll
    for (int rr = 0; rr < 4; rr++) {
        int row = rr * 4 + rsub;
        out[(row0 + row) * D + col] = res[rr];  // 256B contiguous per wave
    }
}

extern "C" void kernel_launch(void* const* d_in, const int* in_sizes, int n_in,
                              void* d_out, int out_size, void* d_ws, size_t ws_size,
                              hipStream_t stream) {
    const float* users_emb = (const float*)d_in[0];
    const float* items_emb = (const float*)d_in[1];
    const float* vals      = (const float*)d_in[2];
    const float* w         = (const float*)d_in[3];
    const int*   rows      = (const int*)d_in[4];
    const int*   cols      = (const int*)d_in[5];
    float* out = (float*)d_out;

    int nnz = in_sizes[2];

    // zero the accumulator (d_out is poisoned 0xAA before every launch)
    hipMemsetAsync(out, 0, (size_t)out_size * sizeof(float), stream);

    // phase 1: scatter-add (4 edges per 256-thread block)
    int nblocks = (nnz + 3) / 4;
    scatter_kernel<<<nblocks, 256, 0, stream>>>(users_emb, items_emb, vals,
                                                rows, cols, out, nnz);

    // phase 2: in-place row transform (16 rows per block; N=500000 divisible by 16)
    int n = NTOT;
    rowgemm_kernel<<<n / 16, 256, 0, stream>>>(out, w, n);
}

// Round 2
// 2534.516 us; speedup vs baseline: 1.0199x; 1.0199x over previous
//
#include <hip/hip_runtime.h>
#include <hip/hip_bf16.h>

#define NUM_USER 300000
#define NUM_ITEM 200000
#define NTOT (NUM_USER + NUM_ITEM)
#define D 64
#define SCAN_ELEMS 2048

// ---------- CSR build ----------

__global__ __launch_bounds__(256) void hist_kernel(
    const int* __restrict__ rows, int* __restrict__ cnt, int nnz)
{
    int e = blockIdx.x * 256 + threadIdx.x;
    if (e < nnz) atomicAdd(&cnt[rows[e]], 1);
}

__global__ __launch_bounds__(256) void scan_reduce(
    const int* __restrict__ cnt, int* __restrict__ bsums, int n)
{
    __shared__ int s[256];
    int base = blockIdx.x * SCAN_ELEMS;
    int sum = 0;
    for (int i = threadIdx.x; i < SCAN_ELEMS; i += 256) {
        int idx = base + i;
        sum += (idx < n) ? cnt[idx] : 0;
    }
    s[threadIdx.x] = sum;
    __syncthreads();
    for (int off = 128; off > 0; off >>= 1) {
        if (threadIdx.x < off) s[threadIdx.x] += s[threadIdx.x + off];
        __syncthreads();
    }
    if (threadIdx.x == 0) bsums[blockIdx.x] = s[0];
}

// single block: exclusive-scan bsums in place; also write ptr[n] = nnz
__global__ __launch_bounds__(256) void scan_bsums(
    int* __restrict__ bsums, int* __restrict__ ptr, int B, int n, int nnz)
{
    __shared__ int s[256];
    int t = threadIdx.x;
    int v = (t < B) ? bsums[t] : 0;
    s[t] = v;
    __syncthreads();
    for (int off = 1; off < 256; off <<= 1) {
        int add = (t >= off) ? s[t - off] : 0;
        __syncthreads();
        s[t] += add;
        __syncthreads();
    }
    if (t < B) bsums[t] = s[t] - v;  // exclusive
    if (t == 0) ptr[n] = nnz;
}

__global__ __launch_bounds__(256) void scan_final(
    const int* __restrict__ cnt, const int* __restrict__ bsums,
    int* __restrict__ ptr, int* __restrict__ tmp, int n)
{
    __shared__ int s[256];
    int base = blockIdx.x * SCAN_ELEMS;
    int t = threadIdx.x;
    int local[8];
    int mysum = 0;
    #pragma unroll
    for (int i = 0; i < 8; i++) {
        int idx = base + t * 8 + i;
        int c = (idx < n) ? cnt[idx] : 0;
        local[i] = mysum;   // exclusive within thread
        mysum += c;
    }
    s[t] = mysum;
    __syncthreads();
    int v = mysum;
    for (int off = 1; off < 256; off <<= 1) {
        int add = (t >= off) ? s[t - off] : 0;
        __syncthreads();
        s[t] += add;
        __syncthreads();
    }
    int thread_base = bsums[blockIdx.x] + s[t] - v;  // exclusive across block
    #pragma unroll
    for (int i = 0; i < 8; i++) {
        int idx = base + t * 8 + i;
        if (idx < n) {
            int p = thread_base + local[i];
            ptr[idx] = p;
            tmp[idx] = p;
        }
    }
}

__global__ __launch_bounds__(256) void permute_kernel(
    const int* __restrict__ rows, int* __restrict__ tmp,
    int* __restrict__ order, int nnz)
{
    int e = blockIdx.x * 256 + threadIdx.x;
    if (e < nnz) {
        int r = rows[e];
        int pos = atomicAdd(&tmp[r], 1);
        order[pos] = e;
    }
}

// ---------- gather: one wave per row, lane = dim ----------

__global__ __launch_bounds__(256) void gather_kernel(
    const float* __restrict__ users_emb,
    const float* __restrict__ items_emb,
    const float* __restrict__ vals,
    const int*   __restrict__ cols,
    const int*   __restrict__ ptr,
    const int*   __restrict__ order,
    float* __restrict__ out, int n)
{
    int r = blockIdx.x * 4 + (threadIdx.x >> 6);
    if (r >= n) return;
    int lane = threadIdx.x & 63;
    int start = ptr[r];
    int end   = ptr[r + 1];
    float acc = 0.f;
    for (int base = start; base < end; base += 64) {
        int m = end - base;          // >=1; lane<m implies lane<min(m,64)
        int c = 0; float v = 0.f;
        if (lane < m) {
            int e = order[base + lane];  // coalesced
            c = cols[e];                 // random 4B (L3)
            v = vals[e];
        }
        int cnt = m < 64 ? m : 64;
        for (int j = 0; j < cnt; j++) {
            int   cj = __shfl(c, j);
            float vj = __shfl(v, j);
            const float* src = (cj < NUM_USER)
                ? users_emb + (size_t)cj * D
                : items_emb + (size_t)(cj - NUM_USER) * D;
            acc = fmaf(vj, src[lane], acc);  // 256B coalesced gather per wave
        }
    }
    out[(size_t)r * D + lane] = acc;
}

// ---------- phase 2: in-place out_row = leaky_relu(agg_row @ w) ----------

__global__ __launch_bounds__(256) void rowgemm_kernel(
    float* __restrict__ out, const float* __restrict__ w, int n)
{
    __shared__ float ws[D * D];   // 16 KB
    __shared__ float as[16 * D];  // 4 KB
    int tid = threadIdx.x;

    const float4* w4 = (const float4*)w;
    float4* ws4 = (float4*)ws;
    #pragma unroll
    for (int i = 0; i < 4; i++) ws4[tid + i * 256] = w4[tid + i * 256];

    size_t row0 = (size_t)blockIdx.x * 16;
    ((float4*)as)[tid] = ((const float4*)(out + row0 * D))[tid];
    __syncthreads();

    int col  = tid & 63;
    int rsub = tid >> 6;
    float res[4];
    #pragma unroll
    for (int rr = 0; rr < 4; rr++) {
        int row = rr * 4 + rsub;
        float acc = 0.f;
        #pragma unroll
        for (int k = 0; k < D; k++) {
            acc = fmaf(as[row * D + k], ws[k * D + col], acc);
        }
        res[rr] = acc > 0.f ? acc : 0.2f * acc;
    }
    #pragma unroll
    for (int rr = 0; rr < 4; rr++) {
        int row = rr * 4 + rsub;
        out[(row0 + row) * D + col] = res[rr];
    }
}

extern "C" void kernel_launch(void* const* d_in, const int* in_sizes, int n_in,
                              void* d_out, int out_size, void* d_ws, size_t ws_size,
                              hipStream_t stream) {
    const float* users_emb = (const float*)d_in[0];
    const float* items_emb = (const float*)d_in[1];
    const float* vals      = (const float*)d_in[2];
    const float* w         = (const float*)d_in[3];
    const int*   rows      = (const int*)d_in[4];
    const int*   cols      = (const int*)d_in[5];
    float* out = (float*)d_out;

    int nnz = in_sizes[2];
    int n   = NTOT;

    // workspace layout (bytes):
    //   cnt   @ 0        : n ints          (2.0 MB)
    //   ptr   @ 2 MB     : n+1 ints        (2.0 MB)
    //   tmp   @ 4 MB     : n ints          (2.0 MB)
    //   bsums @ 6 MB     : 256 ints
    //   order @ 8 MB     : nnz ints        (40 MB)
    char* ws = (char*)d_ws;
    int* cnt   = (int*)(ws);
    int* ptr   = (int*)(ws + (2ull << 20));
    int* tmp   = (int*)(ws + (4ull << 20));
    int* bsums = (int*)(ws + (6ull << 20));
    int* order = (int*)(ws + (8ull << 20));

    hipMemsetAsync(cnt, 0, (size_t)n * sizeof(int), stream);

    int eblocks = (nnz + 255) / 256;
    hist_kernel<<<eblocks, 256, 0, stream>>>(rows, cnt, nnz);

    int B = (n + SCAN_ELEMS - 1) / SCAN_ELEMS;  // 245 <= 256
    scan_reduce<<<B, 256, 0, stream>>>(cnt, bsums, n);
    scan_bsums<<<1, 256, 0, stream>>>(bsums, ptr, B, n, nnz);
    scan_final<<<B, 256, 0, stream>>>(cnt, bsums, ptr, tmp, n);

    permute_kernel<<<eblocks, 256, 0, stream>>>(rows, tmp, order, nnz);

    gather_kernel<<<(n + 3) / 4, 256, 0, stream>>>(
        users_emb, items_emb, vals, cols, ptr, order, out, n);

    rowgemm_kernel<<<n / 16, 256, 0, stream>>>(out, w, n);
}